// Round 6
// baseline (65.660 us; speedup 1.0000x reference)
//
#include <hip/hip_runtime.h>

#define NELEM 21600
#define KSEL 1000
#define MAXB 18
#define NT 1024
#define CAP 2048
#define NCHUNK 4
#define CHUNK (NELEM / NCHUNK)      // 5400
#define NFULL 21                    // 21*1024 = 21504
#define NTAIL (NELEM - NFULL * NT)  // 96

typedef unsigned long long ull;

// monotone map: ascending uint key <-> ascending float
__device__ __forceinline__ unsigned fkey(float f) {
  unsigned u = __float_as_uint(f);
  return (u & 0x80000000u) ? ~u : (u | 0x80000000u);
}
__device__ __forceinline__ float unfkey(unsigned k) {
  unsigned u = (k & 0x80000000u) ? (k ^ 0x80000000u) : ~k;
  return __uint_as_float(u);
}

// ---------------- K1: full-chip strided scan -> coalesced keys + chunk hists ----
__global__ __launch_bounds__(NT) void k1_scan(
    const float* __restrict__ x, unsigned* __restrict__ gkeys,
    unsigned* __restrict__ ghist) {
  const int blk = blockIdx.x;
  const int s = blk / NCHUNK, c = blk % NCHUNK;
  const int t = threadIdx.x;
  const float* xb = x + (size_t)s * NELEM * 6;

  __shared__ unsigned h[2048];
  h[2 * t] = 0u; h[2 * t + 1] = 0u;
  __syncthreads();

  const int base = c * CHUNK;
  unsigned key[6];
  bool on[6];
  #pragma unroll
  for (int k = 0; k < 6; ++k) {
    int o = t + (k << 10);
    on[k] = o < CHUNK;
    int e = base + (on[k] ? o : 0);
    key[k] = fkey(xb[(size_t)e * 6]);
  }
  #pragma unroll
  for (int k = 0; k < 6; ++k) {
    if (on[k]) {
      int e = base + t + (k << 10);
      gkeys[(size_t)s * NELEM + e] = key[k];
      atomicAdd(&h[key[k] >> 21], 1u);
    }
  }
  __syncthreads();
  unsigned* gh = ghist + (size_t)blk * 2048;
  gh[2 * t] = h[2 * t];
  gh[2 * t + 1] = h[2 * t + 1];
}

// Wave-shuffle bucket select over hist[2048]. 16 waves x 128 buckets.
// Picks bucket B with cntGe(B) >= target > cntGe(B+1).
__device__ void select_bucket(const unsigned* hist, unsigned target,
                              volatile unsigned* chunkSuf,  // [16] scratch
                              unsigned* outB, unsigned* outCnt, unsigned* outAbove) {
  const int tid = threadIdx.x;
  const int w = tid >> 6, l = tid & 63;
  unsigned h1 = hist[w * 128 + 2 * l + 1];
  unsigned s = hist[w * 128 + 2 * l] + h1;
  #pragma unroll
  for (int d = 1; d < 64; d <<= 1) {
    unsigned t = __shfl_down(s, d);
    if (l + d < 64) s += t;
  }
  if (l == 0) chunkSuf[w] = s;
  __syncthreads();
  if (w == 0) {
    unsigned ct = (l < 16) ? chunkSuf[l] : 0u;
    unsigned cs = ct;
    #pragma unroll
    for (int d = 1; d < 16; d <<= 1) {
      unsigned t = __shfl_down(cs, d);
      if (l + d < 16) cs += t;
    }
    if (l < 16) chunkSuf[l] = cs - ct;   // count in chunks strictly after l
  }
  __syncthreads();
  unsigned base = chunkSuf[w];
  unsigned sufE = s + base;
  unsigned sN = __shfl_down(s, 1);
  unsigned sufN = ((l < 63) ? sN : 0u) + base;
  unsigned geOdd = sufN + h1;
  if (sufE >= target && geOdd < target) { *outB = w * 128u + 2u * l;     *outCnt = sufE;  *outAbove = geOdd; }
  if (geOdd >= target && sufN < target) { *outB = w * 128u + 2u * l + 1; *outCnt = geOdd; *outAbove = sufN;  }
  __syncthreads();
}

// ---------------- K2: per-sample select + compact + sort + NMS + output --------
__global__ __launch_bounds__(NT, 4) void k2_select(
    const float* __restrict__ x, const float* __restrict__ anch,
    const unsigned* __restrict__ gkeys, const unsigned* __restrict__ ghist,
    float* __restrict__ out) {
  const int s = blockIdx.x;
  const int tid = threadIdx.x;
  const float* xb = x + (size_t)s * NELEM * 6;
  const unsigned* ks = gkeys + (size_t)s * NELEM;

  __shared__ unsigned hist[2048];
  __shared__ unsigned chunkSuf[16];
  __shared__ ull selPk[CAP];
  __shared__ float bX1[KSEL], bY1[KSEL], bX2[KSEL], bY2[KSEL], bAr[KSEL];
  __shared__ unsigned sB, sCnt, sAbove;
  __shared__ unsigned baseKey;
  __shared__ unsigned cnt;
  __shared__ int keptRank[MAXB];
  __shared__ int numKept;

  // ---- pinned prefetch of this thread's 21+1 keys (coalesced, L2/L3-hot) ----
  unsigned kv[NFULL];
  #pragma unroll
  for (int u = 0; u < NFULL; ++u) kv[u] = ks[tid + (u << 10)];
  unsigned ktail = 0u;
  const bool hastail = tid < NTAIL;
  if (hastail) ktail = ks[tid + NFULL * NT];
  asm volatile("" :
      "+v"(kv[0]), "+v"(kv[1]), "+v"(kv[2]), "+v"(kv[3]), "+v"(kv[4]),
      "+v"(kv[5]), "+v"(kv[6]), "+v"(kv[7]), "+v"(kv[8]), "+v"(kv[9]),
      "+v"(kv[10]), "+v"(kv[11]), "+v"(kv[12]), "+v"(kv[13]), "+v"(kv[14]),
      "+v"(kv[15]), "+v"(kv[16]), "+v"(kv[17]), "+v"(kv[18]), "+v"(kv[19]),
      "+v"(kv[20]), "+v"(ktail));

  // ---- sum the 4 chunk histograms ----
  {
    unsigned h0 = 0, h1 = 0;
    #pragma unroll
    for (int c = 0; c < NCHUNK; ++c) {
      const unsigned* gh = ghist + (size_t)(s * NCHUNK + c) * 2048;
      h0 += gh[2 * tid];
      h1 += gh[2 * tid + 1];
    }
    hist[2 * tid] = h0; hist[2 * tid + 1] = h1;
  }
  __syncthreads();
  select_bucket(hist, KSEL, chunkSuf, &sB, &sCnt, &sAbove);
  const unsigned b1 = sB, cnt1 = sCnt, above1 = sAbove;

  if (cnt1 <= CAP) {
    if (tid == 0) { baseKey = b1 << 21; cnt = 0u; }
  } else {
    // rare fat-bucket: refine within bucket b1 on next 11 bits (from registers)
    hist[2 * tid] = 0u; hist[2 * tid + 1] = 0u;
    __syncthreads();
    #pragma unroll
    for (int u = 0; u < NFULL; ++u)
      if ((kv[u] >> 21) == b1) atomicAdd(&hist[(kv[u] >> 10) & 0x7FFu], 1u);
    if (hastail && (ktail >> 21) == b1) atomicAdd(&hist[(ktail >> 10) & 0x7FFu], 1u);
    __syncthreads();
    select_bucket(hist, KSEL - above1, chunkSuf, &sB, &sCnt, &sAbove);
    if (tid == 0) { baseKey = (b1 << 21) | (sB << 10); cnt = 0u; }
  }
  __syncthreads();

  // ---- compact from registers: keys >= baseKey, packed (key, ~idx) ----
  const unsigned TB = baseKey;
  #pragma unroll
  for (int u = 0; u < NFULL; ++u) {
    if (kv[u] >= TB) {
      unsigned p = atomicAdd(&cnt, 1u);
      unsigned i = (unsigned)(tid + (u << 10));
      if (p < CAP) selPk[p] = ((ull)kv[u] << 32) | (unsigned)(~i);
    }
  }
  if (hastail && ktail >= TB) {
    unsigned p = atomicAdd(&cnt, 1u);
    unsigned i = (unsigned)(tid + NFULL * NT);
    if (p < CAP) selPk[p] = ((ull)ktail << 32) | (unsigned)(~i);
  }
  __syncthreads();
  const unsigned realCnt = (cnt < CAP) ? cnt : CAP;
  for (unsigned i = realCnt + tid; i < CAP; i += NT) selPk[i] = 0ull;
  __syncthreads();

  // ---- hybrid bitonic sort 2048 descending ----
  {
    const int w = tid >> 6, L = tid & 63;
    const int ea = (w << 7) | (L << 1);
    ull a = selPk[ea], bb = selPk[ea + 1];
    #pragma unroll
    for (unsigned k = 2; k <= 128; k <<= 1) {
      #pragma unroll
      for (unsigned j = k >> 1; j >= 2; j >>= 1) {
        bool up = ((ea & k) == 0);
        bool lower = ((ea & j) == 0);
        bool takeMax = (up == lower);
        ull oa = __shfl_xor(a, (int)(j >> 1));
        ull ob = __shfl_xor(bb, (int)(j >> 1));
        a  = takeMax ? (a  > oa ? a  : oa) : (a  < oa ? a  : oa);
        bb = takeMax ? (bb > ob ? bb : ob) : (bb < ob ? bb : ob);
      }
      bool up = ((ea & k) == 0);
      ull mx = a > bb ? a : bb, mn = a > bb ? bb : a;
      a = up ? mx : mn; bb = up ? mn : mx;
    }
    selPk[ea] = a; selPk[ea + 1] = bb;
    __syncthreads();
    for (unsigned k = 256; k <= 2048; k <<= 1) {
      for (unsigned j = k >> 1; j >= 128; j >>= 1) {
        unsigned p = (unsigned)tid;
        unsigned vi = ((p & ~(j - 1)) << 1) | (p & (j - 1));
        unsigned li = vi | j;
        ull av = selPk[vi], cv = selPk[li];
        bool doswap = ((vi & k) == 0) ? (av < cv) : (av > cv);
        if (doswap) { selPk[vi] = cv; selPk[li] = av; }
        __syncthreads();
      }
      a = selPk[ea]; bb = selPk[ea + 1];
      bool up = (((unsigned)(w << 7) & k) == 0);   // wave-uniform for k>=256
      #pragma unroll
      for (unsigned j = 64; j >= 2; j >>= 1) {
        bool lower = ((ea & j) == 0);
        bool takeMax = (up == lower);
        ull oa = __shfl_xor(a, (int)(j >> 1));
        ull ob = __shfl_xor(bb, (int)(j >> 1));
        a  = takeMax ? (a  > oa ? a  : oa) : (a  < oa ? a  : oa);
        bb = takeMax ? (bb > ob ? bb : ob) : (bb < ob ? bb : ob);
      }
      ull mx = a > bb ? a : bb, mn = a > bb ? bb : a;
      a = up ? mx : mn; bb = up ? mn : mx;
      selPk[ea] = a; selPk[ea + 1] = bb;
      __syncthreads();
    }
  }

  // ---- decode first 1000 into box arrays for NMS ----
  if (tid < KSEL) {
    unsigned idx = ~(unsigned)selPk[tid];
    const float2* e2 = (const float2*)(xb + (size_t)idx * 6 + 2);
    float2 ra = e2[0], rb = e2[1];
    unsigned pp = (idx / 9u) % 60u;
    unsigned qq = idx / 540u;
    unsigned sr = idx % 9u;
    const float* ap = anch + (((pp * 40u + qq) * 9u + sr) * 4u);
    float ax = ap[0], ay = ap[1], aw = ap[2], ah = ap[3];
    float xc = ra.x * aw + ax;
    float yc = ra.y * ah + ay;
    float w = aw * expf(rb.x);
    float h = ah * expf(rb.y);
    float x1 = xc - 0.5f * w, x2 = xc + 0.5f * w;
    float y1 = yc - 0.5f * h, y2 = yc + 0.5f * h;
    bX1[tid] = x1; bY1[tid] = y1; bX2[tid] = x2; bY2[tid] = y2;
    bAr[tid] = (x2 - x1) * (y2 - y1);
  }
  __syncthreads();

  // ---- greedy NMS on wave 0, early exit at 18 kept ----
  if (tid < 64) {
    const int lane = tid;
    int nk = 0;
    float kx1 = 0.f, ky1 = 0.f, kx2 = 0.f, ky2 = 0.f;  // lane i holds kept box i
    int krank = -1;
    for (int base = 0; base < KSEL && nk < MAXB; base += 64) {
      int c = base + lane;
      bool alive = (c < KSEL);
      int cc = alive ? c : 0;
      float x1 = bX1[cc], y1 = bY1[cc], x2 = bX2[cc], y2 = bY2[cc], ar = bAr[cc];
      for (int i = 0; i < nk; ++i) {
        float px1 = __shfl(kx1, i), py1 = __shfl(ky1, i);
        float px2 = __shfl(kx2, i), py2 = __shfl(ky2, i);
        float iw = fmaxf(fminf(x2, px2) - fmaxf(x1, px1), 0.f);
        float ih = fmaxf(fminf(y2, py2) - fmaxf(y1, py1), 0.f);
        if (iw * ih / ar > 0.5f) alive = false;
      }
      unsigned long long m = __ballot(alive);
      while (m) {
        int i = __builtin_ctzll(m);      // lowest alive lane = best remaining score
        float px1 = __shfl(x1, i), py1 = __shfl(y1, i);
        float px2 = __shfl(x2, i), py2 = __shfl(y2, i);
        if (lane == nk) { kx1 = px1; ky1 = py1; kx2 = px2; ky2 = py2; krank = base + i; }
        ++nk;
        if (nk >= MAXB) break;
        if (alive && lane != i) {
          float iw = fmaxf(fminf(x2, px2) - fmaxf(x1, px1), 0.f);
          float ih = fmaxf(fminf(y2, py2) - fmaxf(y1, py1), 0.f);
          if (iw * ih / ar > 0.5f) alive = false;
        }
        if (lane == i) alive = false;
        m = __ballot(alive);
      }
    }
    if (lane == 0) numKept = nk;
    if (lane < nk) keptRank[lane] = krank;
  }
  __syncthreads();

  // ---- output: kept rows then pad rows cand[j - n]; score from key bits ----
  const int n = numKept;
  if (tid < MAXB) {
    int j = tid;
    int r = (j < n) ? keptRank[j] : (j - n);
    ull pk = selPk[r];
    unsigned idx = ~(unsigned)pk;
    float sc = unfkey((unsigned)(pk >> 32));
    const float2* e2 = (const float2*)(xb + (size_t)idx * 6 + 2);
    float2 ra = e2[0], rb = e2[1];
    unsigned pp = (idx / 9u) % 60u;
    unsigned qq = idx / 540u;
    unsigned sr = idx % 9u;
    const float* ap = anch + (((pp * 40u + qq) * 9u + sr) * 4u);
    float ax = ap[0], ay = ap[1], aw = ap[2], ah = ap[3];
    float xc = ra.x * aw + ax;
    float yc = ra.y * ah + ay;
    float w = aw * expf(rb.x);
    float h = ah * expf(rb.y);
    float* o = out + s * (MAXB * 5) + j * 5;
    o[0] = xc; o[1] = yc; o[2] = w; o[3] = h; o[4] = sc;
  }
}

extern "C" void kernel_launch(void* const* d_in, const int* in_sizes, int n_in,
                              void* d_out, int out_size, void* d_ws, size_t ws_size,
                              hipStream_t stream) {
  const float* x = (const float*)d_in[0];
  const float* anch = (const float*)d_in[1];
  float* out = (float*)d_out;
  const int B = in_sizes[0] / (NELEM * 6);
  unsigned* ghist = (unsigned*)d_ws;                       // B*4*2048 u32
  unsigned* gkeys = ghist + (size_t)B * NCHUNK * 2048;     // B*21600 u32
  k1_scan<<<dim3(B * NCHUNK), dim3(NT), 0, stream>>>(x, gkeys, ghist);
  k2_select<<<dim3(B), dim3(NT), 0, stream>>>(x, anch, gkeys, ghist, out);
}

// Round 7
// 60.928 us; speedup vs baseline: 1.0777x; 1.0777x over previous
//
#include <hip/hip_runtime.h>

#define NELEM 21600
#define KSEL 1000
#define MAXB 18
#define NT 1024
#define CAP 2048
#define NCHUNK 4
#define CHUNK (NELEM / NCHUNK)      // 5400
#define NFULL 21                    // 21*1024 = 21504
#define NTAIL (NELEM - NFULL * NT)  // 96

typedef unsigned long long ull;

// monotone map: ascending uint key <-> ascending float
__device__ __forceinline__ unsigned fkey(float f) {
  unsigned u = __float_as_uint(f);
  return (u & 0x80000000u) ? ~u : (u | 0x80000000u);
}
__device__ __forceinline__ float unfkey(unsigned k) {
  unsigned u = (k & 0x80000000u) ? (k ^ 0x80000000u) : ~k;
  return __uint_as_float(u);
}

// ---------------- K1: full-chip strided scan -> coalesced keys + chunk hists ----
__global__ __launch_bounds__(NT) void k1_scan(
    const float* __restrict__ x, unsigned* __restrict__ gkeys,
    unsigned* __restrict__ ghist) {
  const int blk = blockIdx.x;
  const int s = blk / NCHUNK, c = blk % NCHUNK;
  const int t = threadIdx.x;
  const float* xb = x + (size_t)s * NELEM * 6;

  __shared__ unsigned h[2048];
  h[2 * t] = 0u; h[2 * t + 1] = 0u;
  __syncthreads();

  const int base = c * CHUNK;
  unsigned key[6];
  bool on[6];
  #pragma unroll
  for (int k = 0; k < 6; ++k) {
    int o = t + (k << 10);
    on[k] = o < CHUNK;
    int e = base + (on[k] ? o : 0);
    key[k] = fkey(xb[(size_t)e * 6]);
  }
  #pragma unroll
  for (int k = 0; k < 6; ++k) {
    if (on[k]) {
      int e = base + t + (k << 10);
      gkeys[(size_t)s * NELEM + e] = key[k];
      atomicAdd(&h[key[k] >> 21], 1u);
    }
  }
  __syncthreads();
  unsigned* gh = ghist + (size_t)blk * 2048;
  gh[2 * t] = h[2 * t];
  gh[2 * t + 1] = h[2 * t + 1];
}

// Wave-shuffle bucket select over hist[2048]. 16 waves x 128 buckets.
// Picks bucket B with cntGe(B) >= target > cntGe(B+1).
__device__ void select_bucket(const unsigned* hist, unsigned target,
                              volatile unsigned* chunkSuf,  // [16] scratch
                              unsigned* outB, unsigned* outCnt, unsigned* outAbove) {
  const int tid = threadIdx.x;
  const int w = tid >> 6, l = tid & 63;
  unsigned h1 = hist[w * 128 + 2 * l + 1];
  unsigned s = hist[w * 128 + 2 * l] + h1;
  #pragma unroll
  for (int d = 1; d < 64; d <<= 1) {
    unsigned t = __shfl_down(s, d);
    if (l + d < 64) s += t;
  }
  if (l == 0) chunkSuf[w] = s;
  __syncthreads();
  if (w == 0) {
    unsigned ct = (l < 16) ? chunkSuf[l] : 0u;
    unsigned cs = ct;
    #pragma unroll
    for (int d = 1; d < 16; d <<= 1) {
      unsigned t = __shfl_down(cs, d);
      if (l + d < 16) cs += t;
    }
    if (l < 16) chunkSuf[l] = cs - ct;   // count in chunks strictly after l
  }
  __syncthreads();
  unsigned base = chunkSuf[w];
  unsigned sufE = s + base;
  unsigned sN = __shfl_down(s, 1);
  unsigned sufN = ((l < 63) ? sN : 0u) + base;
  unsigned geOdd = sufN + h1;
  if (sufE >= target && geOdd < target) { *outB = w * 128u + 2u * l;     *outCnt = sufE;  *outAbove = geOdd; }
  if (geOdd >= target && sufN < target) { *outB = w * 128u + 2u * l + 1; *outCnt = geOdd; *outAbove = sufN;  }
  __syncthreads();
}

// ---------------- K2: per-sample select + compact + sort + NMS + output --------
__global__ __launch_bounds__(NT, 4) void k2_select(
    const float* __restrict__ x, const float* __restrict__ anch,
    const unsigned* __restrict__ gkeys, const unsigned* __restrict__ ghist,
    float* __restrict__ out) {
  const int s = blockIdx.x;
  const int tid = threadIdx.x;
  const float* xb = x + (size_t)s * NELEM * 6;
  const unsigned* ks = gkeys + (size_t)s * NELEM;

  __shared__ unsigned hist[2048];
  __shared__ unsigned chunkSuf[16];
  __shared__ ull selPk[CAP];
  __shared__ float bX1[KSEL], bY1[KSEL], bX2[KSEL], bY2[KSEL], bAr[KSEL];
  __shared__ unsigned sB, sCnt, sAbove;
  __shared__ unsigned baseKey;
  __shared__ unsigned cnt;
  __shared__ int keptRank[MAXB];
  __shared__ int numKept;

  // ---- pinned prefetch of this thread's 21+1 keys (coalesced, L2/L3-hot) ----
  unsigned kv[NFULL];
  #pragma unroll
  for (int u = 0; u < NFULL; ++u) kv[u] = ks[tid + (u << 10)];
  unsigned ktail = 0u;
  const bool hastail = tid < NTAIL;
  if (hastail) ktail = ks[tid + NFULL * NT];
  asm volatile("" :
      "+v"(kv[0]), "+v"(kv[1]), "+v"(kv[2]), "+v"(kv[3]), "+v"(kv[4]),
      "+v"(kv[5]), "+v"(kv[6]), "+v"(kv[7]), "+v"(kv[8]), "+v"(kv[9]),
      "+v"(kv[10]), "+v"(kv[11]), "+v"(kv[12]), "+v"(kv[13]), "+v"(kv[14]),
      "+v"(kv[15]), "+v"(kv[16]), "+v"(kv[17]), "+v"(kv[18]), "+v"(kv[19]),
      "+v"(kv[20]), "+v"(ktail));

  // ---- sum the 4 chunk histograms ----
  {
    unsigned h0 = 0, h1 = 0;
    #pragma unroll
    for (int c = 0; c < NCHUNK; ++c) {
      const unsigned* gh = ghist + (size_t)(s * NCHUNK + c) * 2048;
      h0 += gh[2 * tid];
      h1 += gh[2 * tid + 1];
    }
    hist[2 * tid] = h0; hist[2 * tid + 1] = h1;
  }
  __syncthreads();
  select_bucket(hist, KSEL, chunkSuf, &sB, &sCnt, &sAbove);
  const unsigned b1 = sB, cnt1 = sCnt, above1 = sAbove;

  if (cnt1 > 1024) {
    // refine to 22 bits so selected count fits a 1024 sort
    hist[2 * tid] = 0u; hist[2 * tid + 1] = 0u;
    __syncthreads();
    #pragma unroll
    for (int u = 0; u < NFULL; ++u)
      if ((kv[u] >> 21) == b1) atomicAdd(&hist[(kv[u] >> 10) & 0x7FFu], 1u);
    if (hastail && (ktail >> 21) == b1) atomicAdd(&hist[(ktail >> 10) & 0x7FFu], 1u);
    __syncthreads();
    select_bucket(hist, KSEL - above1, chunkSuf, &sB, &sCnt, &sAbove);
    if (tid == 0) { baseKey = (b1 << 21) | (sB << 10); cnt = 0u; }
  } else {
    if (tid == 0) { baseKey = b1 << 21; cnt = 0u; }
  }
  __syncthreads();

  // ---- compact from registers: keys >= baseKey; wave-aggregated counter ----
  const unsigned TB = baseKey;
  const int lw = tid & 63;
  #pragma unroll
  for (int u = 0; u < NFULL; ++u) {
    bool pred = kv[u] >= TB;
    ull mask = __ballot(pred);
    if (mask) {
      int leader = __builtin_ctzll(mask);
      unsigned total = (unsigned)__popcll(mask);
      unsigned basep = 0;
      if (lw == leader) basep = atomicAdd(&cnt, total);
      basep = __shfl(basep, leader);
      if (pred) {
        unsigned p = basep + (unsigned)__popcll(mask & ((1ull << lw) - 1ull));
        unsigned i = (unsigned)(tid + (u << 10));
        if (p < CAP) selPk[p] = ((ull)kv[u] << 32) | (unsigned)(~i);
      }
    }
  }
  if (hastail && ktail >= TB) {
    unsigned p = atomicAdd(&cnt, 1u);
    unsigned i = (unsigned)(tid + NFULL * NT);
    if (p < CAP) selPk[p] = ((ull)ktail << 32) | (unsigned)(~i);
  }
  __syncthreads();
  const unsigned realCnt = (cnt < CAP) ? cnt : CAP;
  const unsigned P = (realCnt <= 1024u) ? 1024u : 2048u;
  for (unsigned i = realCnt + tid; i < P; i += NT) selPk[i] = 0ull;
  __syncthreads();

  if (P == 1024u) {
    // ---- hybrid bitonic sort 1024 descending, 1 elem/thread ----
    ull a = selPk[tid];
    #pragma unroll
    for (unsigned k = 2; k <= 64; k <<= 1) {
      #pragma unroll
      for (unsigned j = k >> 1; j >= 1; j >>= 1) {
        bool up = ((tid & k) == 0);
        bool lower = ((tid & j) == 0);
        bool takeMax = (up == lower);
        ull o = __shfl_xor(a, (int)j);
        a = takeMax ? (a > o ? a : o) : (a < o ? a : o);
      }
    }
    selPk[tid] = a;
    __syncthreads();
    for (unsigned k = 128; k <= 1024; k <<= 1) {
      for (unsigned j = k >> 1; j >= 64; j >>= 1) {
        if (tid < 512) {
          unsigned p = (unsigned)tid;
          unsigned vi = ((p & ~(j - 1)) << 1) | (p & (j - 1));
          unsigned li = vi | j;
          ull av = selPk[vi], cv = selPk[li];
          bool doswap = ((vi & k) == 0) ? (av < cv) : (av > cv);
          if (doswap) { selPk[vi] = cv; selPk[li] = av; }
        }
        __syncthreads();
      }
      a = selPk[tid];
      {
        bool up = ((tid & k) == 0);
        #pragma unroll
        for (unsigned j = 32; j >= 1; j >>= 1) {
          bool lower = ((tid & j) == 0);
          bool takeMax = (up == lower);
          ull o = __shfl_xor(a, (int)j);
          a = takeMax ? (a > o ? a : o) : (a < o ? a : o);
        }
      }
      selPk[tid] = a;
      __syncthreads();
    }
  } else {
    // ---- fallback: hybrid bitonic sort 2048 descending, 2 elem/thread ----
    const int w = tid >> 6, L = tid & 63;
    const int ea = (w << 7) | (L << 1);
    ull a = selPk[ea], bb = selPk[ea + 1];
    #pragma unroll
    for (unsigned k = 2; k <= 128; k <<= 1) {
      #pragma unroll
      for (unsigned j = k >> 1; j >= 2; j >>= 1) {
        bool up = ((ea & k) == 0);
        bool lower = ((ea & j) == 0);
        bool takeMax = (up == lower);
        ull oa = __shfl_xor(a, (int)(j >> 1));
        ull ob = __shfl_xor(bb, (int)(j >> 1));
        a  = takeMax ? (a  > oa ? a  : oa) : (a  < oa ? a  : oa);
        bb = takeMax ? (bb > ob ? bb : ob) : (bb < ob ? bb : ob);
      }
      bool up = ((ea & k) == 0);
      ull mx = a > bb ? a : bb, mn = a > bb ? bb : a;
      a = up ? mx : mn; bb = up ? mn : mx;
    }
    selPk[ea] = a; selPk[ea + 1] = bb;
    __syncthreads();
    for (unsigned k = 256; k <= 2048; k <<= 1) {
      for (unsigned j = k >> 1; j >= 128; j >>= 1) {
        unsigned p = (unsigned)tid;
        unsigned vi = ((p & ~(j - 1)) << 1) | (p & (j - 1));
        unsigned li = vi | j;
        ull av = selPk[vi], cv = selPk[li];
        bool doswap = ((vi & k) == 0) ? (av < cv) : (av > cv);
        if (doswap) { selPk[vi] = cv; selPk[li] = av; }
        __syncthreads();
      }
      a = selPk[ea]; bb = selPk[ea + 1];
      bool up = (((unsigned)(w << 7) & k) == 0);
      #pragma unroll
      for (unsigned j = 64; j >= 2; j >>= 1) {
        bool lower = ((ea & j) == 0);
        bool takeMax = (up == lower);
        ull oa = __shfl_xor(a, (int)(j >> 1));
        ull ob = __shfl_xor(bb, (int)(j >> 1));
        a  = takeMax ? (a  > oa ? a  : oa) : (a  < oa ? a  : oa);
        bb = takeMax ? (bb > ob ? bb : ob) : (bb < ob ? bb : ob);
      }
      ull mx = a > bb ? a : bb, mn = a > bb ? bb : a;
      a = up ? mx : mn; bb = up ? mn : mx;
      selPk[ea] = a; selPk[ea + 1] = bb;
      __syncthreads();
    }
  }

  // ---- decode first 1000 into box arrays for NMS ----
  if (tid < KSEL) {
    unsigned idx = ~(unsigned)selPk[tid];
    const float2* e2 = (const float2*)(xb + (size_t)idx * 6 + 2);
    float2 ra = e2[0], rb = e2[1];
    unsigned pp = (idx / 9u) % 60u;
    unsigned qq = idx / 540u;
    unsigned sr = idx % 9u;
    const float* ap = anch + (((pp * 40u + qq) * 9u + sr) * 4u);
    float ax = ap[0], ay = ap[1], aw = ap[2], ah = ap[3];
    float xc = ra.x * aw + ax;
    float yc = ra.y * ah + ay;
    float w = aw * expf(rb.x);
    float h = ah * expf(rb.y);
    float x1 = xc - 0.5f * w, x2 = xc + 0.5f * w;
    float y1 = yc - 0.5f * h, y2 = yc + 0.5f * h;
    bX1[tid] = x1; bY1[tid] = y1; bX2[tid] = x2; bY2[tid] = y2;
    bAr[tid] = (x2 - x1) * (y2 - y1);
  }
  __syncthreads();

  // ---- in-register NMS on wave 0: <=18 iterations, 16 candidates/lane ----
  if (tid < 64) {
    const int lane = tid;
    float X1[16], Y1[16], X2[16], Y2[16], AR[16];
    unsigned alive = 0u;
    #pragma unroll
    for (int ss = 0; ss < 16; ++ss) {
      int r = lane * 16 + ss;
      bool ok = r < KSEL;
      int rr = ok ? r : 0;
      X1[ss] = bX1[rr]; Y1[ss] = bY1[rr];
      X2[ss] = bX2[rr]; Y2[ss] = bY2[rr]; AR[ss] = bAr[rr];
      alive |= (ok ? 1u : 0u) << ss;
    }
    int nk = 0;
    while (nk < MAXB) {
      int local = alive ? (lane * 16 + (int)__builtin_ctz(alive)) : (1 << 30);
      int m = local;
      #pragma unroll
      for (int d = 1; d < 64; d <<= 1) {
        int o = __shfl_xor(m, d);
        m = o < m ? o : m;
      }
      if (m >= (1 << 30)) break;
      if (lane == 0) keptRank[nk] = m;
      float wx1 = bX1[m], wy1 = bY1[m], wx2 = bX2[m], wy2 = bY2[m];
      ++nk;
      if (alive) {
        #pragma unroll
        for (int ss = 0; ss < 16; ++ss) {
          if (alive & (1u << ss)) {
            float iw = fmaxf(fminf(X2[ss], wx2) - fmaxf(X1[ss], wx1), 0.f);
            float ih = fmaxf(fminf(Y2[ss], wy2) - fmaxf(Y1[ss], wy1), 0.f);
            if (iw * ih / AR[ss] > 0.5f) alive &= ~(1u << ss);
          }
        }
      }
    }
    if (lane == 0) numKept = nk;
  }
  __syncthreads();

  // ---- output: kept rows then pad rows cand[j - n]; score from key bits ----
  const int n = numKept;
  if (tid < MAXB) {
    int j = tid;
    int r = (j < n) ? keptRank[j] : (j - n);
    ull pk = selPk[r];
    unsigned idx = ~(unsigned)pk;
    float sc = unfkey((unsigned)(pk >> 32));
    const float2* e2 = (const float2*)(xb + (size_t)idx * 6 + 2);
    float2 ra = e2[0], rb = e2[1];
    unsigned pp = (idx / 9u) % 60u;
    unsigned qq = idx / 540u;
    unsigned sr = idx % 9u;
    const float* ap = anch + (((pp * 40u + qq) * 9u + sr) * 4u);
    float ax = ap[0], ay = ap[1], aw = ap[2], ah = ap[3];
    float xc = ra.x * aw + ax;
    float yc = ra.y * ah + ay;
    float w = aw * expf(rb.x);
    float h = ah * expf(rb.y);
    float* o = out + s * (MAXB * 5) + j * 5;
    o[0] = xc; o[1] = yc; o[2] = w; o[3] = h; o[4] = sc;
  }
}

extern "C" void kernel_launch(void* const* d_in, const int* in_sizes, int n_in,
                              void* d_out, int out_size, void* d_ws, size_t ws_size,
                              hipStream_t stream) {
  const float* x = (const float*)d_in[0];
  const float* anch = (const float*)d_in[1];
  float* out = (float*)d_out;
  const int B = in_sizes[0] / (NELEM * 6);
  unsigned* ghist = (unsigned*)d_ws;                       // B*4*2048 u32
  unsigned* gkeys = ghist + (size_t)B * NCHUNK * 2048;     // B*21600 u32
  k1_scan<<<dim3(B * NCHUNK), dim3(NT), 0, stream>>>(x, gkeys, ghist);
  k2_select<<<dim3(B), dim3(NT), 0, stream>>>(x, anch, gkeys, ghist, out);
}

// Round 8
// 58.684 us; speedup vs baseline: 1.1189x; 1.0382x over previous
//
#include <hip/hip_runtime.h>

#define NELEM 21600
#define KSEL 1000
#define MAXB 18
#define NT 1024
#define CAP 2048
#define NCHUNK 4
#define QC 8100                     // float4s per K1 block (NQ / NCHUNK)
#define NFULL 21                    // 21*1024 = 21504
#define NTAIL (NELEM - NFULL * NT)  // 96

typedef unsigned long long ull;

// monotone map: ascending uint key <-> ascending float
__device__ __forceinline__ unsigned fkey(float f) {
  unsigned u = __float_as_uint(f);
  return (u & 0x80000000u) ? ~u : (u | 0x80000000u);
}
__device__ __forceinline__ float unfkey(unsigned k) {
  unsigned u = (k & 0x80000000u) ? (k ^ 0x80000000u) : ~k;
  return __uint_as_float(u);
}

// ---------------- K1: full-chip float4-coalesced scan -> keys + chunk hists ----
__global__ __launch_bounds__(NT) void k1_scan(
    const float* __restrict__ x, unsigned* __restrict__ gkeys,
    unsigned* __restrict__ ghist) {
  const int blk = blockIdx.x;
  const int s = blk / NCHUNK, c = blk % NCHUNK;
  const int t = threadIdx.x;
  const float4* xq = (const float4*)(x + (size_t)s * NELEM * 6);
  unsigned* gk = gkeys + (size_t)s * NELEM;

  __shared__ unsigned h[2048];
  h[2 * t] = 0u; h[2 * t + 1] = 0u;
  __syncthreads();

  const int base = c * QC;
  // QC = 8100 = 7*1024 + 932
  #pragma unroll
  for (int k = 0; k < 7; ++k) {
    int g = base + t + (k << 10);
    float4 v = xq[g];
    int r = g % 3;                     // r==0 -> score v.x; r==1 -> score v.z
    if (r == 0) {
      unsigned key = fkey(v.x);
      gk[2 * (g / 3)] = key;
      atomicAdd(&h[key >> 21], 1u);
    } else if (r == 1) {
      unsigned key = fkey(v.z);
      gk[2 * (g / 3) + 1] = key;
      atomicAdd(&h[key >> 21], 1u);
    }
  }
  if (t < QC - 7 * 1024) {
    int g = base + t + (7 << 10);
    float4 v = xq[g];
    int r = g % 3;
    if (r == 0) {
      unsigned key = fkey(v.x);
      gk[2 * (g / 3)] = key;
      atomicAdd(&h[key >> 21], 1u);
    } else if (r == 1) {
      unsigned key = fkey(v.z);
      gk[2 * (g / 3) + 1] = key;
      atomicAdd(&h[key >> 21], 1u);
    }
  }
  __syncthreads();
  unsigned* gh = ghist + (size_t)blk * 2048;
  gh[2 * t] = h[2 * t];
  gh[2 * t + 1] = h[2 * t + 1];
}

// Wave-shuffle bucket select over hist[2048]. 16 waves x 128 buckets.
__device__ void select_bucket(const unsigned* hist, unsigned target,
                              volatile unsigned* chunkSuf,
                              unsigned* outB, unsigned* outCnt, unsigned* outAbove) {
  const int tid = threadIdx.x;
  const int w = tid >> 6, l = tid & 63;
  unsigned h1 = hist[w * 128 + 2 * l + 1];
  unsigned s = hist[w * 128 + 2 * l] + h1;
  #pragma unroll
  for (int d = 1; d < 64; d <<= 1) {
    unsigned t = __shfl_down(s, d);
    if (l + d < 64) s += t;
  }
  if (l == 0) chunkSuf[w] = s;
  __syncthreads();
  if (w == 0) {
    unsigned ct = (l < 16) ? chunkSuf[l] : 0u;
    unsigned cs = ct;
    #pragma unroll
    for (int d = 1; d < 16; d <<= 1) {
      unsigned t = __shfl_down(cs, d);
      if (l + d < 16) cs += t;
    }
    if (l < 16) chunkSuf[l] = cs - ct;
  }
  __syncthreads();
  unsigned base = chunkSuf[w];
  unsigned sufE = s + base;
  unsigned sN = __shfl_down(s, 1);
  unsigned sufN = ((l < 63) ? sN : 0u) + base;
  unsigned geOdd = sufN + h1;
  if (sufE >= target && geOdd < target) { *outB = w * 128u + 2u * l;     *outCnt = sufE;  *outAbove = geOdd; }
  if (geOdd >= target && sufN < target) { *outB = w * 128u + 2u * l + 1; *outCnt = geOdd; *outAbove = sufN;  }
  __syncthreads();
}

// ---------------- K2a: per-sample select + compact + sort -> gsort -------------
__global__ __launch_bounds__(NT, 4) void k2a_sort(
    const unsigned* __restrict__ gkeys, const unsigned* __restrict__ ghist,
    ull* __restrict__ gsort) {
  const int s = blockIdx.x;
  const int tid = threadIdx.x;
  const unsigned* ks = gkeys + (size_t)s * NELEM;

  __shared__ unsigned hist[2048];
  __shared__ unsigned chunkSuf[16];
  __shared__ ull selPk[CAP];
  __shared__ unsigned sB, sCnt, sAbove;
  __shared__ unsigned baseKey;
  __shared__ unsigned cnt;

  // ---- pinned prefetch of this thread's 21+1 keys ----
  unsigned kv[NFULL];
  #pragma unroll
  for (int u = 0; u < NFULL; ++u) kv[u] = ks[tid + (u << 10)];
  unsigned ktail = 0u;
  const bool hastail = tid < NTAIL;
  if (hastail) ktail = ks[tid + NFULL * NT];
  asm volatile("" :
      "+v"(kv[0]), "+v"(kv[1]), "+v"(kv[2]), "+v"(kv[3]), "+v"(kv[4]),
      "+v"(kv[5]), "+v"(kv[6]), "+v"(kv[7]), "+v"(kv[8]), "+v"(kv[9]),
      "+v"(kv[10]), "+v"(kv[11]), "+v"(kv[12]), "+v"(kv[13]), "+v"(kv[14]),
      "+v"(kv[15]), "+v"(kv[16]), "+v"(kv[17]), "+v"(kv[18]), "+v"(kv[19]),
      "+v"(kv[20]), "+v"(ktail));

  // ---- sum the 4 chunk histograms ----
  {
    unsigned h0 = 0, h1 = 0;
    #pragma unroll
    for (int c = 0; c < NCHUNK; ++c) {
      const unsigned* gh = ghist + (size_t)(s * NCHUNK + c) * 2048;
      h0 += gh[2 * tid];
      h1 += gh[2 * tid + 1];
    }
    hist[2 * tid] = h0; hist[2 * tid + 1] = h1;
  }
  __syncthreads();
  select_bucket(hist, KSEL, chunkSuf, &sB, &sCnt, &sAbove);
  const unsigned b1 = sB, cnt1 = sCnt, above1 = sAbove;

  if (cnt1 > 1024) {
    hist[2 * tid] = 0u; hist[2 * tid + 1] = 0u;
    __syncthreads();
    #pragma unroll
    for (int u = 0; u < NFULL; ++u)
      if ((kv[u] >> 21) == b1) atomicAdd(&hist[(kv[u] >> 10) & 0x7FFu], 1u);
    if (hastail && (ktail >> 21) == b1) atomicAdd(&hist[(ktail >> 10) & 0x7FFu], 1u);
    __syncthreads();
    select_bucket(hist, KSEL - above1, chunkSuf, &sB, &sCnt, &sAbove);
    if (tid == 0) { baseKey = (b1 << 21) | (sB << 10); cnt = 0u; }
  } else {
    if (tid == 0) { baseKey = b1 << 21; cnt = 0u; }
  }
  __syncthreads();

  // ---- compact from registers: keys >= baseKey; wave-aggregated counter ----
  const unsigned TB = baseKey;
  const int lw = tid & 63;
  #pragma unroll
  for (int u = 0; u < NFULL; ++u) {
    bool pred = kv[u] >= TB;
    ull mask = __ballot(pred);
    if (mask) {
      int leader = __builtin_ctzll(mask);
      unsigned total = (unsigned)__popcll(mask);
      unsigned basep = 0;
      if (lw == leader) basep = atomicAdd(&cnt, total);
      basep = __shfl(basep, leader);
      if (pred) {
        unsigned p = basep + (unsigned)__popcll(mask & ((1ull << lw) - 1ull));
        unsigned i = (unsigned)(tid + (u << 10));
        if (p < CAP) selPk[p] = ((ull)kv[u] << 32) | (unsigned)(~i);
      }
    }
  }
  if (hastail && ktail >= TB) {
    unsigned p = atomicAdd(&cnt, 1u);
    unsigned i = (unsigned)(tid + NFULL * NT);
    if (p < CAP) selPk[p] = ((ull)ktail << 32) | (unsigned)(~i);
  }
  __syncthreads();
  const unsigned realCnt = (cnt < CAP) ? cnt : CAP;
  const unsigned P = (realCnt <= 1024u) ? 1024u : 2048u;
  for (unsigned i = realCnt + tid; i < P; i += NT) selPk[i] = 0ull;
  __syncthreads();

  if (P == 1024u) {
    ull a = selPk[tid];
    #pragma unroll
    for (unsigned k = 2; k <= 64; k <<= 1) {
      #pragma unroll
      for (unsigned j = k >> 1; j >= 1; j >>= 1) {
        bool up = ((tid & k) == 0);
        bool lower = ((tid & j) == 0);
        bool takeMax = (up == lower);
        ull o = __shfl_xor(a, (int)j);
        a = takeMax ? (a > o ? a : o) : (a < o ? a : o);
      }
    }
    selPk[tid] = a;
    __syncthreads();
    for (unsigned k = 128; k <= 1024; k <<= 1) {
      for (unsigned j = k >> 1; j >= 64; j >>= 1) {
        if (tid < 512) {
          unsigned p = (unsigned)tid;
          unsigned vi = ((p & ~(j - 1)) << 1) | (p & (j - 1));
          unsigned li = vi | j;
          ull av = selPk[vi], cv = selPk[li];
          bool doswap = ((vi & k) == 0) ? (av < cv) : (av > cv);
          if (doswap) { selPk[vi] = cv; selPk[li] = av; }
        }
        __syncthreads();
      }
      a = selPk[tid];
      {
        bool up = ((tid & k) == 0);
        #pragma unroll
        for (unsigned j = 32; j >= 1; j >>= 1) {
          bool lower = ((tid & j) == 0);
          bool takeMax = (up == lower);
          ull o = __shfl_xor(a, (int)j);
          a = takeMax ? (a > o ? a : o) : (a < o ? a : o);
        }
      }
      selPk[tid] = a;
      __syncthreads();
    }
  } else {
    const int w = tid >> 6, L = tid & 63;
    const int ea = (w << 7) | (L << 1);
    ull a = selPk[ea], bb = selPk[ea + 1];
    #pragma unroll
    for (unsigned k = 2; k <= 128; k <<= 1) {
      #pragma unroll
      for (unsigned j = k >> 1; j >= 2; j >>= 1) {
        bool up = ((ea & k) == 0);
        bool lower = ((ea & j) == 0);
        bool takeMax = (up == lower);
        ull oa = __shfl_xor(a, (int)(j >> 1));
        ull ob = __shfl_xor(bb, (int)(j >> 1));
        a  = takeMax ? (a  > oa ? a  : oa) : (a  < oa ? a  : oa);
        bb = takeMax ? (bb > ob ? bb : ob) : (bb < ob ? bb : ob);
      }
      bool up = ((ea & k) == 0);
      ull mx = a > bb ? a : bb, mn = a > bb ? bb : a;
      a = up ? mx : mn; bb = up ? mn : mx;
    }
    selPk[ea] = a; selPk[ea + 1] = bb;
    __syncthreads();
    for (unsigned k = 256; k <= 2048; k <<= 1) {
      for (unsigned j = k >> 1; j >= 128; j >>= 1) {
        unsigned p = (unsigned)tid;
        unsigned vi = ((p & ~(j - 1)) << 1) | (p & (j - 1));
        unsigned li = vi | j;
        ull av = selPk[vi], cv = selPk[li];
        bool doswap = ((vi & k) == 0) ? (av < cv) : (av > cv);
        if (doswap) { selPk[vi] = cv; selPk[li] = av; }
        __syncthreads();
      }
      a = selPk[ea]; bb = selPk[ea + 1];
      bool up = (((unsigned)(w << 7) & k) == 0);
      #pragma unroll
      for (unsigned j = 64; j >= 2; j >>= 1) {
        bool lower = ((ea & j) == 0);
        bool takeMax = (up == lower);
        ull oa = __shfl_xor(a, (int)(j >> 1));
        ull ob = __shfl_xor(bb, (int)(j >> 1));
        a  = takeMax ? (a  > oa ? a  : oa) : (a  < oa ? a  : oa);
        bb = takeMax ? (bb > ob ? bb : ob) : (bb < ob ? bb : ob);
      }
      ull mx = a > bb ? a : bb, mn = a > bb ? bb : a;
      a = up ? mx : mn; bb = up ? mn : mx;
      selPk[ea] = a; selPk[ea + 1] = bb;
      __syncthreads();
    }
  }

  // ---- store sorted top-1024 (descending) ----
  gsort[(size_t)s * 1024 + tid] = selPk[tid];
}

// ---------------- K2b: decode + ballot-NMS + output ----------------------------
__global__ __launch_bounds__(NT, 2) void k2b_nms(
    const float* __restrict__ x, const float* __restrict__ anch,
    const ull* __restrict__ gsort, float* __restrict__ out) {
  const int s = blockIdx.x;
  const int tid = threadIdx.x;
  const float* xb = x + (size_t)s * NELEM * 6;

  __shared__ ull pkL[1024];
  __shared__ float px1[64 * 17], py1[64 * 17], px2[64 * 17], py2[64 * 17], par[64 * 17];
  __shared__ int keptRank[MAXB];
  __shared__ int numKept;

  ull pk = gsort[(size_t)s * 1024 + tid];
  pkL[tid] = pk;
  if (tid < KSEL) {
    unsigned idx = ~(unsigned)pk;
    const float2* e2 = (const float2*)(xb + (size_t)idx * 6 + 2);
    float2 ra = e2[0], rb = e2[1];
    unsigned pp = (idx / 9u) % 60u;
    unsigned qq = idx / 540u;
    unsigned sr = idx % 9u;
    const float* ap = anch + (((pp * 40u + qq) * 9u + sr) * 4u);
    float ax = ap[0], ay = ap[1], aw = ap[2], ah = ap[3];
    float xc = ra.x * aw + ax;
    float yc = ra.y * ah + ay;
    float w = aw * expf(rb.x);
    float h = ah * expf(rb.y);
    float x1 = xc - 0.5f * w, x2 = xc + 0.5f * w;
    float y1 = yc - 0.5f * h, y2 = yc + 0.5f * h;
    int a = (tid >> 4) * 17 + (tid & 15);    // stride-17: conflict-free both sides
    px1[a] = x1; py1[a] = y1; px2[a] = x2; py2[a] = y2;
    par[a] = (x2 - x1) * (y2 - y1);
  }
  __syncthreads();

  // ---- ballot-NMS on wave 0: sorted order, 16 consecutive ranks per lane ----
  if (tid < 64) {
    const int lane = tid;
    float X1[16], Y1[16], X2[16], Y2[16], AR[16];
    unsigned alive = 0u;
    #pragma unroll
    for (int ss = 0; ss < 16; ++ss) {
      int r = lane * 16 + ss;
      int a = lane * 17 + ss;
      X1[ss] = px1[a]; Y1[ss] = py1[a];
      X2[ss] = px2[a]; Y2[ss] = py2[a]; AR[ss] = par[a];
      alive |= (r < KSEL ? 1u : 0u) << ss;
    }
    int nk = 0;
    while (nk < MAXB) {
      ull bal = __ballot(alive != 0u);
      if (!bal) break;
      int F = __builtin_ctzll(bal);                    // lane holding best alive
      int myss = (int)__builtin_ctz(alive | 0x10000u);
      int ssw = __shfl(myss, F);
      int m = F * 16 + ssw;                            // global rank of winner
      if (lane == 0) keptRank[nk] = m;
      int am = (m >> 4) * 17 + (m & 15);
      float wx1 = px1[am], wy1 = py1[am], wx2 = px2[am], wy2 = py2[am];
      ++nk;
      if (nk >= MAXB) break;
      #pragma unroll
      for (int ss = 0; ss < 16; ++ss) {
        if (alive & (1u << ss)) {
          float iw = fmaxf(fminf(X2[ss], wx2) - fmaxf(X1[ss], wx1), 0.f);
          float ih = fmaxf(fminf(Y2[ss], wy2) - fmaxf(Y1[ss], wy1), 0.f);
          if (iw * ih / AR[ss] > 0.5f) alive &= ~(1u << ss);  // winner self-clears
        }
      }
    }
    if (lane == 0) numKept = nk;
  }
  __syncthreads();

  // ---- output: kept rows then pad rows cand[j - n]; score from key bits ----
  const int n = numKept;
  if (tid < MAXB) {
    int j = tid;
    int r = (j < n) ? keptRank[j] : (j - n);
    ull pkr = pkL[r];
    unsigned idx = ~(unsigned)pkr;
    float sc = unfkey((unsigned)(pkr >> 32));
    const float2* e2 = (const float2*)(xb + (size_t)idx * 6 + 2);
    float2 ra = e2[0], rb = e2[1];
    unsigned pp = (idx / 9u) % 60u;
    unsigned qq = idx / 540u;
    unsigned sr = idx % 9u;
    const float* ap = anch + (((pp * 40u + qq) * 9u + sr) * 4u);
    float ax = ap[0], ay = ap[1], aw = ap[2], ah = ap[3];
    float xc = ra.x * aw + ax;
    float yc = ra.y * ah + ay;
    float w = aw * expf(rb.x);
    float h = ah * expf(rb.y);
    float* o = out + s * (MAXB * 5) + j * 5;
    o[0] = xc; o[1] = yc; o[2] = w; o[3] = h; o[4] = sc;
  }
}

extern "C" void kernel_launch(void* const* d_in, const int* in_sizes, int n_in,
                              void* d_out, int out_size, void* d_ws, size_t ws_size,
                              hipStream_t stream) {
  const float* x = (const float*)d_in[0];
  const float* anch = (const float*)d_in[1];
  float* out = (float*)d_out;
  const int B = in_sizes[0] / (NELEM * 6);
  unsigned* ghist = (unsigned*)d_ws;                         // B*4*2048 u32
  unsigned* gkeys = ghist + (size_t)B * NCHUNK * 2048;       // B*21600 u32
  ull* gsort = (ull*)(gkeys + (size_t)B * NELEM);            // B*1024 u64
  k1_scan<<<dim3(B * NCHUNK), dim3(NT), 0, stream>>>(x, gkeys, ghist);
  k2a_sort<<<dim3(B), dim3(NT), 0, stream>>>(gkeys, ghist, gsort);
  k2b_nms<<<dim3(B), dim3(NT), 0, stream>>>(x, anch, gsort, out);
}